// Round 4
// baseline (49.649 us; speedup 1.0000x reference)
//
#include <hip/hip_runtime.h>

#define DT      0.001f
#define MAXU    0.1f

typedef float f32x4 __attribute__((ext_vector_type(4)));

struct R8 { float o0, o1, x0, x1, n00, n01, n10, n11; };

__device__ __forceinline__ R8 rcell_one(
    float s0, float s1, float d0, float d1,
    float c00, float c01, float c10, float c11,
    float C00, float C01, float C10, float C11,
    float A00, float A01, float A10, float A11)
{
    R8 r;
    // output = (C @ s) * DT
    r.o0 = (C00 * s0 + C01 * s1) * DT;
    r.o1 = (C10 * s0 + C11 * s1) * DT;

    // xicov = cov @ C^T : xi[i][k] = sum_j cov[i][j] * C[k][j]
    float xi00 = c00 * C00 + c01 * C01;
    float xi01 = c00 * C10 + c01 * C11;
    float xi10 = c10 * C00 + c11 * C01;
    float xi11 = c10 * C10 + c11 * C11;

    // M = A - xicov @ C
    float m00 = A00 - (xi00 * C00 + xi01 * C10);
    float m01 = A01 - (xi00 * C01 + xi01 * C11);
    float m10 = A10 - (xi10 * C00 + xi11 * C10);
    float m11 = A11 - (xi10 * C01 + xi11 * C11);

    // dx = M @ s * DT + xi @ d
    float dx0 = (m00 * s0 + m01 * s1) * DT + xi00 * d0 + xi01 * d1;
    float dx1 = (m10 * s0 + m11 * s1) * DT + xi10 * d0 + xi11 * d1;
    dx0 = fminf(fmaxf(dx0, -MAXU), MAXU);
    dx1 = fminf(fmaxf(dx1, -MAXU), MAXU);
    r.x0 = s0 + dx0;
    r.x1 = s1 + dx1;

    // cov_dt = cov@A + A@cov - xi@xi^T
    float ca00 = c00 * A00 + c01 * A10, ca01 = c00 * A01 + c01 * A11;
    float ca10 = c10 * A00 + c11 * A10, ca11 = c10 * A01 + c11 * A11;
    float ac00 = A00 * c00 + A01 * c10, ac01 = A00 * c01 + A01 * c11;
    float ac10 = A10 * c00 + A11 * c10, ac11 = A10 * c01 + A11 * c11;
    float xx00 = xi00 * xi00 + xi01 * xi01;
    float xx01 = xi00 * xi10 + xi01 * xi11;   // == xx10
    float xx11 = xi10 * xi10 + xi11 * xi11;

    float cd00 = ca00 + ac00 - xx00;
    float cd01 = ca01 + ac01 - xx01;
    float cd10 = ca10 + ac10 - xx01;
    float cd11 = ca11 + ac11 - xx11;

    r.n00 = fminf(fmaxf(c00 + cd00 * DT, -1.f), 1.f);
    r.n01 = fminf(fmaxf(c01 + cd01 * DT, -1.f), 1.f);
    r.n10 = fminf(fmaxf(c10 + cd10 * DT, -1.f), 1.f);
    r.n11 = fminf(fmaxf(c11 + cd11 * DT, -1.f), 1.f);
    return r;
}

__device__ __forceinline__ void do_pair(
    int pair, const f32x4* __restrict__ dy4, const f32x4* __restrict__ sts4,
    const f32x4* __restrict__ cov4,
    f32x4* __restrict__ o4, f32x4* __restrict__ x4, f32x4* __restrict__ c4,
    float C00, float C01, float C10, float C11,
    float A00, float A01, float A10, float A11)
{
    f32x4 dv = dy4[pair];
    f32x4 sv = sts4[pair];
    f32x4 c0 = cov4[2 * (size_t)pair];
    f32x4 c1 = cov4[2 * (size_t)pair + 1];

    R8 a = rcell_one(sv.x, sv.y, dv.x, dv.y, c0.x, c0.y, c0.z, c0.w,
                     C00, C01, C10, C11, A00, A01, A10, A11);
    R8 b = rcell_one(sv.z, sv.w, dv.z, dv.w, c1.x, c1.y, c1.z, c1.w,
                     C00, C01, C10, C11, A00, A01, A10, A11);

    f32x4 ov = { a.o0, a.o1, b.o0, b.o1 };
    f32x4 xv = { a.x0, a.x1, b.x0, b.x1 };
    f32x4 n0 = { a.n00, a.n01, a.n10, a.n11 };
    f32x4 n1 = { b.n00, b.n01, b.n10, b.n11 };

    __builtin_nontemporal_store(ov, &o4[pair]);
    __builtin_nontemporal_store(xv, &x4[pair]);
    __builtin_nontemporal_store(n0, &c4[2 * (size_t)pair]);
    __builtin_nontemporal_store(n1, &c4[2 * (size_t)pair + 1]);
}

__global__ __launch_bounds__(256) void rcell_kernel(
    const float* __restrict__ dy, const float* __restrict__ sts,
    const float* __restrict__ cov, const float* __restrict__ Cm,
    const float* __restrict__ Am,
    float* __restrict__ out_o, float* __restrict__ out_x,
    float* __restrict__ out_c, int npairs)
{
    const int nthreads = gridDim.x * blockDim.x;   // == npairs/2
    const int tid = blockIdx.x * blockDim.x + threadIdx.x;

    // wave-uniform small matrices (scalar loads, L2-resident)
    const float C00 = Cm[0], C01 = Cm[1], C10 = Cm[2], C11 = Cm[3];
    const float A00 = Am[0], A01 = Am[1], A10 = Am[2], A11 = Am[3];

    const f32x4* dy4  = reinterpret_cast<const f32x4*>(dy);
    const f32x4* sts4 = reinterpret_cast<const f32x4*>(sts);
    const f32x4* cov4 = reinterpret_cast<const f32x4*>(cov);
    f32x4* o4 = reinterpret_cast<f32x4*>(out_o);
    f32x4* x4 = reinterpret_cast<f32x4*>(out_x);
    f32x4* c4 = reinterpret_cast<f32x4*>(out_c);

    // two stride-split pairs per thread: both fully coalesced
    do_pair(tid,            dy4, sts4, cov4, o4, x4, c4,
            C00, C01, C10, C11, A00, A01, A10, A11);
    do_pair(tid + nthreads, dy4, sts4, cov4, o4, x4, c4,
            C00, C01, C10, C11, A00, A01, A10, A11);
}

extern "C" void kernel_launch(void* const* d_in, const int* in_sizes, int n_in,
                              void* d_out, int out_size, void* d_ws, size_t ws_size,
                              hipStream_t stream) {
    const float* dy  = (const float*)d_in[0];
    const float* sts = (const float*)d_in[1];
    const float* cov = (const float*)d_in[2];
    const float* Cm  = (const float*)d_in[3];
    const float* Am  = (const float*)d_in[4];

    const int B = in_sizes[0] / 2;          // dy is [B,2]
    float* out = (float*)d_out;
    float* out_o = out;                     // [B,2]
    float* out_x = out + (size_t)B * 2;     // [B,2]
    float* out_c = out + (size_t)B * 4;     // [B,2,2]

    const int npairs = B / 2;               // 2097152
    const int threads = 256;
    const int blocks = npairs / 2 / threads; // 2 pairs per thread, exact cover
    rcell_kernel<<<blocks, threads, 0, stream>>>(
        dy, sts, cov, Cm, Am, out_o, out_x, out_c, npairs);
}

// Round 5
// 44.235 us; speedup vs baseline: 1.1224x; 1.1224x over previous
//
#include <hip/hip_runtime.h>

#define DT      0.001f
#define MAXU    0.1f

typedef float f32x4 __attribute__((ext_vector_type(4)));

struct R8 { float o0, o1, x0, x1, n00, n01, n10, n11; };

__device__ __forceinline__ R8 rcell_one(
    float s0, float s1, float d0, float d1,
    float c00, float c01, float c10, float c11,
    float C00, float C01, float C10, float C11,
    float A00, float A01, float A10, float A11)
{
    R8 r;
    // output = (C @ s) * DT
    r.o0 = (C00 * s0 + C01 * s1) * DT;
    r.o1 = (C10 * s0 + C11 * s1) * DT;

    // xicov = cov @ C^T : xi[i][k] = sum_j cov[i][j] * C[k][j]
    float xi00 = c00 * C00 + c01 * C01;
    float xi01 = c00 * C10 + c01 * C11;
    float xi10 = c10 * C00 + c11 * C01;
    float xi11 = c10 * C10 + c11 * C11;

    // M = A - xicov @ C
    float m00 = A00 - (xi00 * C00 + xi01 * C10);
    float m01 = A01 - (xi00 * C01 + xi01 * C11);
    float m10 = A10 - (xi10 * C00 + xi11 * C10);
    float m11 = A11 - (xi10 * C01 + xi11 * C11);

    // dx = M @ s * DT + xi @ d
    float dx0 = (m00 * s0 + m01 * s1) * DT + xi00 * d0 + xi01 * d1;
    float dx1 = (m10 * s0 + m11 * s1) * DT + xi10 * d0 + xi11 * d1;
    dx0 = fminf(fmaxf(dx0, -MAXU), MAXU);
    dx1 = fminf(fmaxf(dx1, -MAXU), MAXU);
    r.x0 = s0 + dx0;
    r.x1 = s1 + dx1;

    // cov_dt = cov@A + A@cov - xi@xi^T
    float ca00 = c00 * A00 + c01 * A10, ca01 = c00 * A01 + c01 * A11;
    float ca10 = c10 * A00 + c11 * A10, ca11 = c10 * A01 + c11 * A11;
    float ac00 = A00 * c00 + A01 * c10, ac01 = A00 * c01 + A01 * c11;
    float ac10 = A10 * c00 + A11 * c10, ac11 = A10 * c01 + A11 * c11;
    float xx00 = xi00 * xi00 + xi01 * xi01;
    float xx01 = xi00 * xi10 + xi01 * xi11;   // == xx10
    float xx11 = xi10 * xi10 + xi11 * xi11;

    float cd00 = ca00 + ac00 - xx00;
    float cd01 = ca01 + ac01 - xx01;
    float cd10 = ca10 + ac10 - xx01;
    float cd11 = ca11 + ac11 - xx11;

    r.n00 = fminf(fmaxf(c00 + cd00 * DT, -1.f), 1.f);
    r.n01 = fminf(fmaxf(c01 + cd01 * DT, -1.f), 1.f);
    r.n10 = fminf(fmaxf(c10 + cd10 * DT, -1.f), 1.f);
    r.n11 = fminf(fmaxf(c11 + cd11 * DT, -1.f), 1.f);
    return r;
}

__device__ __forceinline__ void do_pair(
    int pair, const f32x4* __restrict__ dy4, const f32x4* __restrict__ sts4,
    const f32x4* __restrict__ cov4,
    f32x4* __restrict__ o4, f32x4* __restrict__ x4, f32x4* __restrict__ c4,
    float C00, float C01, float C10, float C11,
    float A00, float A01, float A10, float A11)
{
    f32x4 dv = dy4[pair];
    f32x4 sv = sts4[pair];
    f32x4 c0 = cov4[2 * (size_t)pair];
    f32x4 c1 = cov4[2 * (size_t)pair + 1];

    R8 a = rcell_one(sv.x, sv.y, dv.x, dv.y, c0.x, c0.y, c0.z, c0.w,
                     C00, C01, C10, C11, A00, A01, A10, A11);
    R8 b = rcell_one(sv.z, sv.w, dv.z, dv.w, c1.x, c1.y, c1.z, c1.w,
                     C00, C01, C10, C11, A00, A01, A10, A11);

    f32x4 ov = { a.o0, a.o1, b.o0, b.o1 };
    f32x4 xv = { a.x0, a.x1, b.x0, b.x1 };
    f32x4 n0 = { a.n00, a.n01, a.n10, a.n11 };
    f32x4 n1 = { b.n00, b.n01, b.n10, b.n11 };

    o4[pair] = ov;
    x4[pair] = xv;
    c4[2 * (size_t)pair]     = n0;
    c4[2 * (size_t)pair + 1] = n1;
}

__global__ __launch_bounds__(256) void rcell_kernel(
    const float* __restrict__ dy, const float* __restrict__ sts,
    const float* __restrict__ cov, const float* __restrict__ Cm,
    const float* __restrict__ Am,
    float* __restrict__ out_o, float* __restrict__ out_x,
    float* __restrict__ out_c, int npairs)
{
    const int nthreads = gridDim.x * blockDim.x;   // == npairs/2
    const int tid = blockIdx.x * blockDim.x + threadIdx.x;

    // wave-uniform small matrices (scalar loads, L2-resident)
    const float C00 = Cm[0], C01 = Cm[1], C10 = Cm[2], C11 = Cm[3];
    const float A00 = Am[0], A01 = Am[1], A10 = Am[2], A11 = Am[3];

    const f32x4* dy4  = reinterpret_cast<const f32x4*>(dy);
    const f32x4* sts4 = reinterpret_cast<const f32x4*>(sts);
    const f32x4* cov4 = reinterpret_cast<const f32x4*>(cov);
    f32x4* o4 = reinterpret_cast<f32x4*>(out_o);
    f32x4* x4 = reinterpret_cast<f32x4*>(out_x);
    f32x4* c4 = reinterpret_cast<f32x4*>(out_c);

    // two stride-split pairs per thread: both fully coalesced
    do_pair(tid,            dy4, sts4, cov4, o4, x4, c4,
            C00, C01, C10, C11, A00, A01, A10, A11);
    do_pair(tid + nthreads, dy4, sts4, cov4, o4, x4, c4,
            C00, C01, C10, C11, A00, A01, A10, A11);
}

extern "C" void kernel_launch(void* const* d_in, const int* in_sizes, int n_in,
                              void* d_out, int out_size, void* d_ws, size_t ws_size,
                              hipStream_t stream) {
    const float* dy  = (const float*)d_in[0];
    const float* sts = (const float*)d_in[1];
    const float* cov = (const float*)d_in[2];
    const float* Cm  = (const float*)d_in[3];
    const float* Am  = (const float*)d_in[4];

    const int B = in_sizes[0] / 2;          // dy is [B,2]
    float* out = (float*)d_out;
    float* out_o = out;                     // [B,2]
    float* out_x = out + (size_t)B * 2;     // [B,2]
    float* out_c = out + (size_t)B * 4;     // [B,2,2]

    const int npairs = B / 2;               // 2097152
    const int threads = 256;
    const int blocks = npairs / 2 / threads; // 2 pairs per thread, exact cover
    rcell_kernel<<<blocks, threads, 0, stream>>>(
        dy, sts, cov, Cm, Am, out_o, out_x, out_c, npairs);
}